// Round 4
// baseline (125.299 us; speedup 1.0000x reference)
//
#include <hip/hip_runtime.h>

// FlowWarpConsistencyLoss: B=16, C=3, H=W=512, flow 2x128x128.
// Pass 1: grayscale pred_next -> ZERO-PADDED buffer (576x576 per image) in d_ws.
//         Padding makes per-corner OOB-zeroing free and tile staging maskless.
// Pass 2: block = 64x16 output tile. Stage 116x64 gray tile (24px halo) + 6 flow
//         rows into LDS via float4 (coalesced); all gathers hit LDS. Rare
//         out-of-tile pixels fall back to clamped reads of the padded buffer.
// Rationale: R1-R3 scaling shows time ~ global lane-request count (~4cy each);
//         this cuts global lane-requests/thread from 40 to ~13.

constexpr int B  = 16;
constexpr int H  = 512;
constexpr int W  = 512;
constexpr int FH = 128;
constexpr int FW = 128;
constexpr int HW  = H * W;
constexpr int IMG = 3 * HW;
constexpr int FHW = FH * FW;
constexpr float EPS = 0.001f;

constexpr int P    = 32;            // zero padding on every side
constexpr int PW   = W + 2 * P;     // 576
constexpr int PH   = H + 2 * P;     // 576
constexpr int PIMG = PW * PH;       // 331776
constexpr int PQ   = PH * (PW / 4); // 82944 float4s per padded image

constexpr int TX = 64, TY = 16;     // output tile per block
constexpr int TW = 116, TH = 64;    // staged tile: 24+64+28 x, 24+16+24 y
constexpr int TILE_F = TW * TH;     // 7424 floats
constexpr int FROWS  = 6;
constexpr int FLOW_F = 2 * FROWS * FW; // 1536 floats

// ---------------- pass 1: gray(next) into padded buffer ----------------
__global__ __launch_bounds__(256) void pad_gray_kernel(
    const float* __restrict__ nxt, float* __restrict__ g)
{
    const int q  = blockIdx.x * 256 + threadIdx.x;
    const int b  = q / PQ;
    const int r  = q - b * PQ;
    const int py = r / (PW / 4);
    const int qx = r - py * (PW / 4);
    const int y  = py - P;
    const int xs = qx * 4 - P;
    float4 o = make_float4(0.f, 0.f, 0.f, 0.f);
    if ((unsigned)y < (unsigned)H && (unsigned)xs <= (unsigned)(W - 4)) {
        const float* __restrict__ nb = nxt + (long)b * IMG + y * W + xs;
        const float4 rr = *(const float4*)(nb);
        const float4 gg = *(const float4*)(nb + HW);
        const float4 bl = *(const float4*)(nb + 2 * HW);
        o.x = 0.299f * rr.x + 0.587f * gg.x + 0.114f * bl.x;
        o.y = 0.299f * rr.y + 0.587f * gg.y + 0.114f * bl.y;
        o.z = 0.299f * rr.z + 0.587f * gg.z + 0.114f * bl.z;
        o.w = 0.299f * rr.w + 0.587f * gg.w + 0.114f * bl.w;
    }
    *(float4*)(g + (long)b * PIMG + py * PW + qx * 4) = o;
}

// ---------------- pass 2: LDS-tiled warp + loss ----------------
__global__ __launch_bounds__(256) void loss_kernel(
    const float* __restrict__ prev, const float* __restrict__ gpad,
    const float* __restrict__ flow, double* __restrict__ loss_acc,
    unsigned int* __restrict__ cnt_acc)
{
    __shared__ float sm[TILE_F + FLOW_F];

    // 4096 blocks; XCD-chunked: 8 XCDs x 512 contiguous (= 2 images each).
    const int bid = ((blockIdx.x & 7) << 9) | (blockIdx.x >> 3);
    const int b   = bid >> 8;
    const int t   = bid & 255;
    const int tx  = t & 7;        // x tile (64 wide)
    const int ty  = t >> 3;       // y stripe (16 tall)
    const int x0t = tx * TX;
    const int y0t = ty * TY;

    const float fr = (float)(127.0 / 511.0);
    const int fy_lo = (int)((float)y0t * fr);

    const float* __restrict__ gb = gpad + (long)b * PIMG;

    // ---- stage gray tile: actual coords y in [y0t-24, y0t+40), x in [x0t-24, x0t+92)
    {
        const float* __restrict__ src = gb + (y0t + 8) * PW + (x0t + 8);
        for (int it = threadIdx.x; it < TH * 29; it += 256) {
            const int r = it / 29, c = it - r * 29;
            const float4 v = *(const float4*)(src + r * PW + c * 4);
            *(float4*)(sm + r * TW + c * 4) = v;
        }
        // ---- stage 6 flow rows (u then v)
        const float* __restrict__ fsrc = flow + (long)b * 2 * FHW;
        for (int it = threadIdx.x; it < 2 * FROWS * 32; it += 256) {
            const int c    = it / (FROWS * 32);
            const int rr   = (it - c * (FROWS * 32)) >> 5;
            const int c4   = it & 31;
            const int frow = min(fy_lo + rr, FH - 1);
            const float4 v = *(const float4*)(fsrc + c * FHW + frow * FW + c4 * 4);
            *(float4*)(sm + TILE_F + c * (FROWS * FW) + rr * FW + c4 * 4) = v;
        }
    }

    // ---- prev grayscale: thread = 4 consecutive x in one row (3 float4 loads)
    const int xq = threadIdx.x & 15;
    const int yl = threadIdx.x >> 4;
    const int y  = y0t + yl;
    const int xb = x0t + xq * 4;
    const float* __restrict__ pb = prev + (long)b * IMG + y * W + xb;
    const float4 pr  = *(const float4*)(pb);
    const float4 pgc = *(const float4*)(pb + HW);
    const float4 plc = *(const float4*)(pb + 2 * HW);
    const float pg[4] = {
        0.299f * pr.x + 0.587f * pgc.x + 0.114f * plc.x,
        0.299f * pr.y + 0.587f * pgc.y + 0.114f * plc.y,
        0.299f * pr.z + 0.587f * pgc.z + 0.114f * plc.z,
        0.299f * pr.w + 0.587f * pgc.w + 0.114f * plc.w };

    __syncthreads();

    // ---- flow values for this thread (row-shared fy, 3 columns cover 4 pixels)
    const float syf = (float)y * fr;
    const int   fy0 = (int)syf;
    const float wy  = syf - (float)fy0;
    const int r0 = fy0 - fy_lo;
    const int r1 = min(fy0 + 1, FH - 1) - fy_lo;

    const float sxfb = (float)xb * fr;
    const int F  = (int)sxfb;
    const int F2 = min(F + 2, FW - 1);
    const float* __restrict__ su = sm + TILE_F;
    const float* __restrict__ sv = su + FROWS * FW;
    const float u0a = su[r0 * FW + F], u0b = su[r0 * FW + F + 1], u0c = su[r0 * FW + F2];
    const float u1a = su[r1 * FW + F], u1b = su[r1 * FW + F + 1], u1c = su[r1 * FW + F2];
    const float v0a = sv[r0 * FW + F], v0b = sv[r0 * FW + F + 1], v0c = sv[r0 * FW + F2];
    const float v1a = sv[r1 * FW + F], v1b = sv[r1 * FW + F + 1], v1c = sv[r1 * FW + F2];

    double lsum = 0.0;
    unsigned int lcnt = 0;

    #pragma unroll
    for (int i = 0; i < 4; ++i) {
        const int x = xb + i;
        const float sxf = (float)x * fr;
        const int   fx0 = (int)sxf;
        const float wx  = sxf - (float)fx0;
        const int   d   = fx0 - F;   // 0 or 1

        const float u00 = d ? u0b : u0a, u01 = d ? u0c : u0b;
        const float u10 = d ? u1b : u1a, u11 = d ? u1c : u1b;
        const float v00 = d ? v0b : v0a, v01 = d ? v0c : v0b;
        const float v10 = d ? v1b : v1a, v11 = d ? v1c : v1b;

        // row-lerp then col-lerp (reference op order), then *4 scale
        const float uc0 = u00 * (1.0f - wy) + u10 * wy;
        const float uc1 = u01 * (1.0f - wy) + u11 * wy;
        const float vc0 = v00 * (1.0f - wy) + v10 * wy;
        const float vc1 = v01 * (1.0f - wy) + v11 * wy;
        const float u = (uc0 * (1.0f - wx) + uc1 * wx) * 4.0f;
        const float v = (vc0 * (1.0f - wx) + vc1 * wx) * 4.0f;

        const float gx = (float)x + u;
        const float gy = (float)y + v;
        const float vm = ((gx >= 0.0f) & (gx <= (float)(W - 1)) &
                          (gy >= 0.0f) & (gy <= (float)(H - 1))) ? 1.0f : 0.0f;

        const float gxf = floorf(gx), gyf = floorf(gy);
        const float wwx = gx - gxf,  wwy = gy - gyf;
        const int ix0 = (int)gxf, iy0 = (int)gyf;

        const int cx = ix0 - (x0t - 24);   // tile col of c00
        const int ry = iy0 - (y0t - 24);   // tile row of c00
        float c00, c01, c10, c11;
        if ((unsigned)cx <= (unsigned)(TW - 2) && (unsigned)ry <= (unsigned)(TH - 2)) {
            const int la = ry * TW + cx;
            c00 = sm[la];      c01 = sm[la + 1];
            c10 = sm[la + TW]; c11 = sm[la + TW + 1];
        } else {
            // rare: clamp into padded region (zeros outside image -> per-corner
            // semantics still exact for any pixel that is valid)
            const int iyc = min(max(iy0, -P), PH - P - 2);
            const int ixc = min(max(ix0, -P), PW - P - 2);
            const float* __restrict__ gp = gb + (iyc + P) * PW + (ixc + P);
            c00 = gp[0];  c01 = gp[1];
            c10 = gp[PW]; c11 = gp[PW + 1];
        }

        const float warped = c00 * (1.0f - wwx) * (1.0f - wwy)
                           + c01 * wwx * (1.0f - wwy)
                           + c10 * (1.0f - wwx) * wwy
                           + c11 * wwx * wwy;
        const float diff = pg[i] - warped;
        const float l = sqrtf(diff * diff + EPS * EPS);
        lsum += (double)(l * vm);
        lcnt += (unsigned int)vm;
    }

    // ---- wave64 + block reduce ----
    #pragma unroll
    for (int off = 32; off > 0; off >>= 1) {
        lsum += __shfl_down(lsum, off);
        lcnt += __shfl_down(lcnt, off);
    }
    __shared__ double s_sum[4];
    __shared__ unsigned int s_cnt[4];
    const int wid = threadIdx.x >> 6, lane = threadIdx.x & 63;
    if (lane == 0) { s_sum[wid] = lsum; s_cnt[wid] = lcnt; }
    __syncthreads();
    if (threadIdx.x == 0) {
        double tt = s_sum[0] + s_sum[1] + s_sum[2] + s_sum[3];
        unsigned int c = s_cnt[0] + s_cnt[1] + s_cnt[2] + s_cnt[3];
        atomicAdd(loss_acc, tt);
        atomicAdd(cnt_acc, c);
    }
}

// ---------------- fallback single-pass (if ws too small) ----------------
__device__ __forceinline__ float gray3(const float* __restrict__ img, int off) {
    return 0.299f * img[off] + 0.587f * img[HW + off] + 0.114f * img[2 * HW + off];
}

__global__ __launch_bounds__(256) void flow_loss_mono_kernel(
    const float* __restrict__ prev, const float* __restrict__ nxt,
    const float* __restrict__ flow, double* __restrict__ loss_acc,
    unsigned int* __restrict__ cnt_acc)
{
    const int nquad = B * HW / 4;
    const float fr = (float)(127.0 / 511.0);
    double lsum = 0.0;
    unsigned int lcnt = 0;
    for (int q = blockIdx.x * blockDim.x + threadIdx.x; q < nquad;
         q += gridDim.x * blockDim.x) {
        const int pix = q * 4;
        const int b   = pix >> 18;
        const int rem = pix & (HW - 1);
        const int y   = rem >> 9;
        const int x0  = rem & 511;
        const float* __restrict__ pb = prev + (long)b * IMG;
        const float* __restrict__ nb = nxt  + (long)b * IMG;
        const float* __restrict__ fu = flow + (long)b * 2 * FHW;
        const float* __restrict__ fv = fu + FHW;
        const float syf = (float)y * fr;
        const int   fy0 = (int)syf;
        const int   fy1 = min(fy0 + 1, FH - 1);
        const float wy  = syf - (float)fy0;
        #pragma unroll
        for (int i = 0; i < 4; ++i) {
            const int x = x0 + i;
            const float sxf = (float)x * fr;
            const int   fx0 = (int)sxf;
            const int   fx1 = min(fx0 + 1, FW - 1);
            const float wx  = sxf - (float)fx0;
            const float uc0 = fu[fy0 * FW + fx0] * (1.0f - wy) + fu[fy1 * FW + fx0] * wy;
            const float uc1 = fu[fy0 * FW + fx1] * (1.0f - wy) + fu[fy1 * FW + fx1] * wy;
            const float vc0 = fv[fy0 * FW + fx0] * (1.0f - wy) + fv[fy1 * FW + fx0] * wy;
            const float vc1 = fv[fy0 * FW + fx1] * (1.0f - wy) + fv[fy1 * FW + fx1] * wy;
            const float u = (uc0 * (1.0f - wx) + uc1 * wx) * 4.0f;
            const float v = (vc0 * (1.0f - wx) + vc1 * wx) * 4.0f;
            const float gx = (float)x + u;
            const float gy = (float)y + v;
            const float vm = ((gx >= 0.0f) & (gx <= (float)(W - 1)) &
                              (gy >= 0.0f) & (gy <= (float)(H - 1))) ? 1.0f : 0.0f;
            const float gxf = floorf(gx), gyf = floorf(gy);
            const float wwx = gx - gxf, wwy = gy - gyf;
            const int ix0 = (int)gxf, iy0 = (int)gyf;
            const int xc0 = min(max(ix0, 0), W - 1), xc1 = min(max(ix0 + 1, 0), W - 1);
            const int yc0 = min(max(iy0, 0), H - 1), yc1 = min(max(iy0 + 1, 0), H - 1);
            const float okx0 = (ix0 >= 0 && ix0 < W) ? 1.f : 0.f;
            const float okx1 = (ix0 + 1 >= 0 && ix0 + 1 < W) ? 1.f : 0.f;
            const float oky0 = (iy0 >= 0 && iy0 < H) ? 1.f : 0.f;
            const float oky1 = (iy0 + 1 >= 0 && iy0 + 1 < H) ? 1.f : 0.f;
            const float c00 = gray3(nb, yc0 * W + xc0) * oky0 * okx0;
            const float c01 = gray3(nb, yc0 * W + xc1) * oky0 * okx1;
            const float c10 = gray3(nb, yc1 * W + xc0) * oky1 * okx0;
            const float c11 = gray3(nb, yc1 * W + xc1) * oky1 * okx1;
            const float warped = c00 * (1.0f - wwx) * (1.0f - wwy)
                               + c01 * wwx * (1.0f - wwy)
                               + c10 * (1.0f - wwx) * wwy
                               + c11 * wwx * wwy;
            const float pgv = gray3(pb, y * W + x);
            const float diff = pgv - warped;
            const float l = sqrtf(diff * diff + EPS * EPS);
            lsum += (double)(l * vm);
            lcnt += (unsigned int)vm;
        }
    }
    #pragma unroll
    for (int off = 32; off > 0; off >>= 1) {
        lsum += __shfl_down(lsum, off);
        lcnt += __shfl_down(lcnt, off);
    }
    __shared__ double s_sum[4];
    __shared__ unsigned int s_cnt[4];
    const int wid = threadIdx.x >> 6, lane = threadIdx.x & 63;
    if (lane == 0) { s_sum[wid] = lsum; s_cnt[wid] = lcnt; }
    __syncthreads();
    if (threadIdx.x == 0) {
        double t = s_sum[0] + s_sum[1] + s_sum[2] + s_sum[3];
        unsigned int c = s_cnt[0] + s_cnt[1] + s_cnt[2] + s_cnt[3];
        atomicAdd(loss_acc, t);
        atomicAdd(cnt_acc, c);
    }
}

__global__ void finalize_kernel(const double* __restrict__ loss_acc,
                                const unsigned int* __restrict__ cnt_acc,
                                float* __restrict__ out)
{
    double c = (double)(*cnt_acc);
    if (c < 1.0) c = 1.0;
    const float loss = (float)(*loss_acc / c);
    out[0] = loss;
    out[1] = loss;
}

extern "C" void kernel_launch(void* const* d_in, const int* in_sizes, int n_in,
                              void* d_out, int out_size, void* d_ws, size_t ws_size,
                              hipStream_t stream) {
    const float* prev = (const float*)d_in[0];
    const float* nxt  = (const float*)d_in[1];
    const float* flow = (const float*)d_in[2];
    float* out = (float*)d_out;

    double* loss_acc = (double*)d_ws;
    unsigned int* cnt_acc = (unsigned int*)((char*)d_ws + 8);
    const size_t pad_bytes = (size_t)B * PIMG * sizeof(float);   // 21.2 MB

    hipMemsetAsync(d_ws, 0, 16, stream);   // ws is NOT re-poisoned between replays

    if (ws_size >= 256 + pad_bytes) {
        float* gbuf = (float*)((char*)d_ws + 256);
        pad_gray_kernel<<<dim3(B * PQ / 256), dim3(256), 0, stream>>>(nxt, gbuf);
        loss_kernel<<<dim3(4096), dim3(256), 0, stream>>>(
            prev, gbuf, flow, loss_acc, cnt_acc);
    } else {
        flow_loss_mono_kernel<<<dim3(2048), dim3(256), 0, stream>>>(
            prev, nxt, flow, loss_acc, cnt_acc);
    }
    finalize_kernel<<<dim3(1), dim3(1), 0, stream>>>(loss_acc, cnt_acc, out);
}

// Round 5
// 47.326 us; speedup vs baseline: 2.6476x; 2.6476x over previous
//
#include <hip/hip_runtime.h>

// FlowWarpConsistencyLoss: B=16, C=3, H=W=512, flow 2x128x128.
// Pass 1: grayscale pred_next -> ZERO-PADDED buffer (576x576/img) in d_ws.
// Pass 2: block = 64x16 tile; stage 116x64 gray tile + 6 flow rows in LDS;
//         all warp gathers hit LDS; per-block partial (double,uint) -> d_ws slot.
// Pass 3: single-block tree reduce of 4096 partials -> out.
// R4->R5: REMOVED the single-address atomicAdd(double) (CAS-loop storm with
//         4096 contenders was the ~90us invariant across R2-R4).

constexpr int B  = 16;
constexpr int H  = 512;
constexpr int W  = 512;
constexpr int FH = 128;
constexpr int FW = 128;
constexpr int HW  = H * W;
constexpr int IMG = 3 * HW;
constexpr int FHW = FH * FW;
constexpr float EPS = 0.001f;

constexpr int P    = 32;            // zero padding on every side
constexpr int PW   = W + 2 * P;     // 576
constexpr int PH   = H + 2 * P;     // 576
constexpr int PIMG = PW * PH;
constexpr int PQ   = PH * (PW / 4);

constexpr int TX = 64, TY = 16;     // output tile per block
constexpr int TW = 116, TH = 64;    // staged tile
constexpr int TILE_F = TW * TH;
constexpr int FROWS  = 6;
constexpr int FLOW_F = 2 * FROWS * FW;

constexpr int NB = 4096;            // blocks in pass 2

// ---------------- pass 1: gray(next) into padded buffer ----------------
__global__ __launch_bounds__(256) void pad_gray_kernel(
    const float* __restrict__ nxt, float* __restrict__ g)
{
    const int q  = blockIdx.x * 256 + threadIdx.x;
    const int b  = q / PQ;
    const int r  = q - b * PQ;
    const int py = r / (PW / 4);
    const int qx = r - py * (PW / 4);
    const int y  = py - P;
    const int xs = qx * 4 - P;
    float4 o = make_float4(0.f, 0.f, 0.f, 0.f);
    if ((unsigned)y < (unsigned)H && (unsigned)xs <= (unsigned)(W - 4)) {
        const float* __restrict__ nb = nxt + (long)b * IMG + y * W + xs;
        const float4 rr = *(const float4*)(nb);
        const float4 gg = *(const float4*)(nb + HW);
        const float4 bl = *(const float4*)(nb + 2 * HW);
        o.x = 0.299f * rr.x + 0.587f * gg.x + 0.114f * bl.x;
        o.y = 0.299f * rr.y + 0.587f * gg.y + 0.114f * bl.y;
        o.z = 0.299f * rr.z + 0.587f * gg.z + 0.114f * bl.z;
        o.w = 0.299f * rr.w + 0.587f * gg.w + 0.114f * bl.w;
    }
    *(float4*)(g + (long)b * PIMG + py * PW + qx * 4) = o;
}

// ---------------- pass 2: LDS-tiled warp + loss, partials out ----------------
__global__ __launch_bounds__(256) void loss_kernel(
    const float* __restrict__ prev, const float* __restrict__ gpad,
    const float* __restrict__ flow, double* __restrict__ psum,
    unsigned int* __restrict__ pcnt)
{
    __shared__ float sm[TILE_F + FLOW_F];

    // XCD-chunked: 8 XCDs x 512 contiguous blocks (= 2 images each).
    const int bid = ((blockIdx.x & 7) << 9) | (blockIdx.x >> 3);
    const int b   = bid >> 8;
    const int t   = bid & 255;
    const int tx  = t & 7;
    const int ty  = t >> 3;
    const int x0t = tx * TX;
    const int y0t = ty * TY;

    const float fr = (float)(127.0 / 511.0);
    const int fy_lo = (int)((float)y0t * fr);

    const float* __restrict__ gb = gpad + (long)b * PIMG;

    // ---- stage gray tile: y in [y0t-24, y0t+40), x in [x0t-24, x0t+92)
    {
        const float* __restrict__ src = gb + (y0t + 8) * PW + (x0t + 8);
        for (int it = threadIdx.x; it < TH * 29; it += 256) {
            const int r = it / 29, c = it - r * 29;
            const float4 v = *(const float4*)(src + r * PW + c * 4);
            *(float4*)(sm + r * TW + c * 4) = v;
        }
        const float* __restrict__ fsrc = flow + (long)b * 2 * FHW;
        for (int it = threadIdx.x; it < 2 * FROWS * 32; it += 256) {
            const int c    = it / (FROWS * 32);
            const int rr   = (it - c * (FROWS * 32)) >> 5;
            const int c4   = it & 31;
            const int frow = min(fy_lo + rr, FH - 1);
            const float4 v = *(const float4*)(fsrc + c * FHW + frow * FW + c4 * 4);
            *(float4*)(sm + TILE_F + c * (FROWS * FW) + rr * FW + c4 * 4) = v;
        }
    }

    // ---- prev grayscale: thread = 4 consecutive x in one row
    const int xq = threadIdx.x & 15;
    const int yl = threadIdx.x >> 4;
    const int y  = y0t + yl;
    const int xb = x0t + xq * 4;
    const float* __restrict__ pb = prev + (long)b * IMG + y * W + xb;
    const float4 pr  = *(const float4*)(pb);
    const float4 pgc = *(const float4*)(pb + HW);
    const float4 plc = *(const float4*)(pb + 2 * HW);
    const float pg[4] = {
        0.299f * pr.x + 0.587f * pgc.x + 0.114f * plc.x,
        0.299f * pr.y + 0.587f * pgc.y + 0.114f * plc.y,
        0.299f * pr.z + 0.587f * pgc.z + 0.114f * plc.z,
        0.299f * pr.w + 0.587f * pgc.w + 0.114f * plc.w };

    __syncthreads();

    // ---- flow values (row-shared fy; 3 columns cover the 4 pixels)
    const float syf = (float)y * fr;
    const int   fy0 = (int)syf;
    const float wy  = syf - (float)fy0;
    const int r0 = fy0 - fy_lo;
    const int r1 = min(fy0 + 1, FH - 1) - fy_lo;

    const float sxfb = (float)xb * fr;
    const int F  = (int)sxfb;
    const int F2 = min(F + 2, FW - 1);
    const float* __restrict__ su = sm + TILE_F;
    const float* __restrict__ sv = su + FROWS * FW;
    const float u0a = su[r0 * FW + F], u0b = su[r0 * FW + F + 1], u0c = su[r0 * FW + F2];
    const float u1a = su[r1 * FW + F], u1b = su[r1 * FW + F + 1], u1c = su[r1 * FW + F2];
    const float v0a = sv[r0 * FW + F], v0b = sv[r0 * FW + F + 1], v0c = sv[r0 * FW + F2];
    const float v1a = sv[r1 * FW + F], v1b = sv[r1 * FW + F + 1], v1c = sv[r1 * FW + F2];

    double lsum = 0.0;
    unsigned int lcnt = 0;

    #pragma unroll
    for (int i = 0; i < 4; ++i) {
        const int x = xb + i;
        const float sxf = (float)x * fr;
        const int   fx0 = (int)sxf;
        const float wx  = sxf - (float)fx0;
        const int   d   = fx0 - F;   // 0 or 1

        const float u00 = d ? u0b : u0a, u01 = d ? u0c : u0b;
        const float u10 = d ? u1b : u1a, u11 = d ? u1c : u1b;
        const float v00 = d ? v0b : v0a, v01 = d ? v0c : v0b;
        const float v10 = d ? v1b : v1a, v11 = d ? v1c : v1b;

        const float uc0 = u00 * (1.0f - wy) + u10 * wy;
        const float uc1 = u01 * (1.0f - wy) + u11 * wy;
        const float vc0 = v00 * (1.0f - wy) + v10 * wy;
        const float vc1 = v01 * (1.0f - wy) + v11 * wy;
        const float u = (uc0 * (1.0f - wx) + uc1 * wx) * 4.0f;
        const float v = (vc0 * (1.0f - wx) + vc1 * wx) * 4.0f;

        const float gx = (float)x + u;
        const float gy = (float)y + v;
        const float vm = ((gx >= 0.0f) & (gx <= (float)(W - 1)) &
                          (gy >= 0.0f) & (gy <= (float)(H - 1))) ? 1.0f : 0.0f;

        const float gxf = floorf(gx), gyf = floorf(gy);
        const float wwx = gx - gxf,  wwy = gy - gyf;
        const int ix0 = (int)gxf, iy0 = (int)gyf;

        const int cx = ix0 - (x0t - 24);
        const int ry = iy0 - (y0t - 24);
        float c00, c01, c10, c11;
        if ((unsigned)cx <= (unsigned)(TW - 2) && (unsigned)ry <= (unsigned)(TH - 2)) {
            const int la = ry * TW + cx;
            c00 = sm[la];      c01 = sm[la + 1];
            c10 = sm[la + TW]; c11 = sm[la + TW + 1];
        } else {
            const int iyc = min(max(iy0, -P), PH - P - 2);
            const int ixc = min(max(ix0, -P), PW - P - 2);
            const float* __restrict__ gp = gb + (iyc + P) * PW + (ixc + P);
            c00 = gp[0];  c01 = gp[1];
            c10 = gp[PW]; c11 = gp[PW + 1];
        }

        const float warped = c00 * (1.0f - wwx) * (1.0f - wwy)
                           + c01 * wwx * (1.0f - wwy)
                           + c10 * (1.0f - wwx) * wwy
                           + c11 * wwx * wwy;
        const float diff = pg[i] - warped;
        const float l = sqrtf(diff * diff + EPS * EPS);
        lsum += (double)(l * vm);
        lcnt += (unsigned int)vm;
    }

    // ---- wave64 + block reduce; ONE partial store per block (no atomics) ----
    #pragma unroll
    for (int off = 32; off > 0; off >>= 1) {
        lsum += __shfl_down(lsum, off);
        lcnt += __shfl_down(lcnt, off);
    }
    __shared__ double s_sum[4];
    __shared__ unsigned int s_cnt[4];
    const int wid = threadIdx.x >> 6, lane = threadIdx.x & 63;
    if (lane == 0) { s_sum[wid] = lsum; s_cnt[wid] = lcnt; }
    __syncthreads();
    if (threadIdx.x == 0) {
        psum[blockIdx.x] = s_sum[0] + s_sum[1] + s_sum[2] + s_sum[3];
        pcnt[blockIdx.x] = s_cnt[0] + s_cnt[1] + s_cnt[2] + s_cnt[3];
    }
}

// ---------------- pass 3: reduce partials ----------------
__global__ __launch_bounds__(256) void reduce_kernel(
    const double* __restrict__ psum, const unsigned int* __restrict__ pcnt,
    int nb, float* __restrict__ out)
{
    double s = 0.0;
    unsigned long long c = 0;
    for (int i = threadIdx.x; i < nb; i += 256) {
        s += psum[i];
        c += (unsigned long long)pcnt[i];
    }
    #pragma unroll
    for (int off = 32; off > 0; off >>= 1) {
        s += __shfl_down(s, off);
        c += __shfl_down(c, off);
    }
    __shared__ double ss[4];
    __shared__ unsigned long long sc[4];
    const int wid = threadIdx.x >> 6, lane = threadIdx.x & 63;
    if (lane == 0) { ss[wid] = s; sc[wid] = c; }
    __syncthreads();
    if (threadIdx.x == 0) {
        double ts = ss[0] + ss[1] + ss[2] + ss[3];
        double tc = (double)(sc[0] + sc[1] + sc[2] + sc[3]);
        if (tc < 1.0) tc = 1.0;
        const float loss = (float)(ts / tc);
        out[0] = loss;
        out[1] = loss;
    }
}

// ---------------- fallback single-pass (if ws too small) ----------------
__device__ __forceinline__ float gray3(const float* __restrict__ img, int off) {
    return 0.299f * img[off] + 0.587f * img[HW + off] + 0.114f * img[2 * HW + off];
}

__global__ __launch_bounds__(256) void flow_loss_mono_kernel(
    const float* __restrict__ prev, const float* __restrict__ nxt,
    const float* __restrict__ flow, double* __restrict__ psum,
    unsigned int* __restrict__ pcnt)
{
    const int nquad = B * HW / 4;
    const float fr = (float)(127.0 / 511.0);
    double lsum = 0.0;
    unsigned int lcnt = 0;
    for (int q = blockIdx.x * blockDim.x + threadIdx.x; q < nquad;
         q += gridDim.x * blockDim.x) {
        const int pix = q * 4;
        const int b   = pix >> 18;
        const int rem = pix & (HW - 1);
        const int y   = rem >> 9;
        const int x0  = rem & 511;
        const float* __restrict__ pb = prev + (long)b * IMG;
        const float* __restrict__ nb = nxt  + (long)b * IMG;
        const float* __restrict__ fu = flow + (long)b * 2 * FHW;
        const float* __restrict__ fv = fu + FHW;
        const float syf = (float)y * fr;
        const int   fy0 = (int)syf;
        const int   fy1 = min(fy0 + 1, FH - 1);
        const float wy  = syf - (float)fy0;
        #pragma unroll
        for (int i = 0; i < 4; ++i) {
            const int x = x0 + i;
            const float sxf = (float)x * fr;
            const int   fx0 = (int)sxf;
            const int   fx1 = min(fx0 + 1, FW - 1);
            const float wx  = sxf - (float)fx0;
            const float uc0 = fu[fy0 * FW + fx0] * (1.0f - wy) + fu[fy1 * FW + fx0] * wy;
            const float uc1 = fu[fy0 * FW + fx1] * (1.0f - wy) + fu[fy1 * FW + fx1] * wy;
            const float vc0 = fv[fy0 * FW + fx0] * (1.0f - wy) + fv[fy1 * FW + fx0] * wy;
            const float vc1 = fv[fy0 * FW + fx1] * (1.0f - wy) + fv[fy1 * FW + fx1] * wy;
            const float u = (uc0 * (1.0f - wx) + uc1 * wx) * 4.0f;
            const float v = (vc0 * (1.0f - wx) + vc1 * wx) * 4.0f;
            const float gx = (float)x + u;
            const float gy = (float)y + v;
            const float vm = ((gx >= 0.0f) & (gx <= (float)(W - 1)) &
                              (gy >= 0.0f) & (gy <= (float)(H - 1))) ? 1.0f : 0.0f;
            const float gxf = floorf(gx), gyf = floorf(gy);
            const float wwx = gx - gxf, wwy = gy - gyf;
            const int ix0 = (int)gxf, iy0 = (int)gyf;
            const int xc0 = min(max(ix0, 0), W - 1), xc1 = min(max(ix0 + 1, 0), W - 1);
            const int yc0 = min(max(iy0, 0), H - 1), yc1 = min(max(iy0 + 1, 0), H - 1);
            const float okx0 = (ix0 >= 0 && ix0 < W) ? 1.f : 0.f;
            const float okx1 = (ix0 + 1 >= 0 && ix0 + 1 < W) ? 1.f : 0.f;
            const float oky0 = (iy0 >= 0 && iy0 < H) ? 1.f : 0.f;
            const float oky1 = (iy0 + 1 >= 0 && iy0 + 1 < H) ? 1.f : 0.f;
            const float c00 = gray3(nb, yc0 * W + xc0) * oky0 * okx0;
            const float c01 = gray3(nb, yc0 * W + xc1) * oky0 * okx1;
            const float c10 = gray3(nb, yc1 * W + xc0) * oky1 * okx0;
            const float c11 = gray3(nb, yc1 * W + xc1) * oky1 * okx1;
            const float warped = c00 * (1.0f - wwx) * (1.0f - wwy)
                               + c01 * wwx * (1.0f - wwy)
                               + c10 * (1.0f - wwx) * wwy
                               + c11 * wwx * wwy;
            const float pgv = gray3(pb, y * W + x);
            const float diff = pgv - warped;
            const float l = sqrtf(diff * diff + EPS * EPS);
            lsum += (double)(l * vm);
            lcnt += (unsigned int)vm;
        }
    }
    #pragma unroll
    for (int off = 32; off > 0; off >>= 1) {
        lsum += __shfl_down(lsum, off);
        lcnt += __shfl_down(lcnt, off);
    }
    __shared__ double s_sum[4];
    __shared__ unsigned int s_cnt[4];
    const int wid = threadIdx.x >> 6, lane = threadIdx.x & 63;
    if (lane == 0) { s_sum[wid] = lsum; s_cnt[wid] = lcnt; }
    __syncthreads();
    if (threadIdx.x == 0) {
        psum[blockIdx.x] = s_sum[0] + s_sum[1] + s_sum[2] + s_sum[3];
        pcnt[blockIdx.x] = s_cnt[0] + s_cnt[1] + s_cnt[2] + s_cnt[3];
    }
}

extern "C" void kernel_launch(void* const* d_in, const int* in_sizes, int n_in,
                              void* d_out, int out_size, void* d_ws, size_t ws_size,
                              hipStream_t stream) {
    const float* prev = (const float*)d_in[0];
    const float* nxt  = (const float*)d_in[1];
    const float* flow = (const float*)d_in[2];
    float* out = (float*)d_out;

    // ws layout: [0, NB*8)       double partial sums
    //            [NB*8, NB*12)   uint partial counts
    //            [4096-aligned]  padded gray buffer
    double* psum = (double*)d_ws;
    unsigned int* pcnt = (unsigned int*)((char*)d_ws + NB * 8);
    const size_t part_bytes = NB * 12;
    const size_t gbuf_off = (part_bytes + 4095) & ~(size_t)4095;
    const size_t pad_bytes = (size_t)B * PIMG * sizeof(float);   // 21.2 MB

    if (ws_size >= gbuf_off + pad_bytes) {
        float* gbuf = (float*)((char*)d_ws + gbuf_off);
        pad_gray_kernel<<<dim3(B * PQ / 256), dim3(256), 0, stream>>>(nxt, gbuf);
        loss_kernel<<<dim3(NB), dim3(256), 0, stream>>>(
            prev, gbuf, flow, psum, pcnt);
        reduce_kernel<<<dim3(1), dim3(256), 0, stream>>>(psum, pcnt, NB, out);
    } else {
        flow_loss_mono_kernel<<<dim3(2048), dim3(256), 0, stream>>>(
            prev, nxt, flow, psum, pcnt);
        reduce_kernel<<<dim3(1), dim3(256), 0, stream>>>(psum, pcnt, 2048, out);
    }
}

// Round 6
// 36.670 us; speedup vs baseline: 3.4170x; 1.2906x over previous
//
#include <hip/hip_runtime.h>

// FlowWarpConsistencyLoss: B=16, C=3, H=W=512, flow 2x128x128.
// Pass 1: grayscale pred_next -> ZERO-PADDED fp16 buffer (576x576/img) in d_ws.
// Pass 2: block = 64x32 tile; stage 120x80 fp16 gray tile + 10 flow rows (f32)
//         into LDS; all warp gathers hit LDS; per-block partial -> d_ws slot.
// Pass 3: single-block reduce of 2048 partials -> out.
// R5->R6: fp16 gray (halves BW + LDS), 64x32 tiles (occupancy 26%->~45%,
//         staging overlap 121->38MB), 8px/thread.
// fp16 error budget: gray in [0,1], |err| <= 5e-4 per corner; worst-case bias
// on the mean << 3.77e-3 threshold.

typedef _Float16 half8 __attribute__((ext_vector_type(8)));

constexpr int B  = 16;
constexpr int H  = 512;
constexpr int W  = 512;
constexpr int FH = 128;
constexpr int FW = 128;
constexpr int HW  = H * W;
constexpr int IMG = 3 * HW;
constexpr int FHW = FH * FW;
constexpr float EPS = 0.001f;

constexpr int P    = 32;            // zero padding on every side
constexpr int PW   = W + 2 * P;     // 576
constexpr int PH   = H + 2 * P;     // 576
constexpr int PIMG = PW * PH;       // halves per padded image
constexpr int PQ8  = PH * (PW / 8); // 41472 half8-chunks per padded image

constexpr int TX = 64, TY = 32;     // output tile per block
constexpr int TW = 120, TH = 80;    // staged tile (halo 24; covers |disp|<=20)
constexpr int FROWS  = 10;
constexpr int FLOW_F = 2 * FROWS * FW;

constexpr int NB = 2048;            // blocks in pass 2

// ---------------- pass 1: gray(next) into padded fp16 buffer ----------------
__global__ __launch_bounds__(256) void pad_gray_kernel(
    const float* __restrict__ nxt, _Float16* __restrict__ g)
{
    const int q  = blockIdx.x * 256 + threadIdx.x;   // half8 chunk index
    const int b  = q / PQ8;
    const int r  = q - b * PQ8;
    const int py = r / (PW / 8);
    const int qx = r - py * (PW / 8);
    const int y  = py - P;
    const int xs = qx * 8 - P;
    half8 o = (half8)0;
    if ((unsigned)y < (unsigned)H && (unsigned)xs <= (unsigned)(W - 8)) {
        const float* __restrict__ nb = nxt + (long)b * IMG + y * W + xs;
        #pragma unroll
        for (int h = 0; h < 2; ++h) {
            const float4 rr = *(const float4*)(nb + 4 * h);
            const float4 gg = *(const float4*)(nb + HW + 4 * h);
            const float4 bl = *(const float4*)(nb + 2 * HW + 4 * h);
            o[4 * h + 0] = (_Float16)(0.299f * rr.x + 0.587f * gg.x + 0.114f * bl.x);
            o[4 * h + 1] = (_Float16)(0.299f * rr.y + 0.587f * gg.y + 0.114f * bl.y);
            o[4 * h + 2] = (_Float16)(0.299f * rr.z + 0.587f * gg.z + 0.114f * bl.z);
            o[4 * h + 3] = (_Float16)(0.299f * rr.w + 0.587f * gg.w + 0.114f * bl.w);
        }
    }
    *(half8*)(g + (long)b * PIMG + py * PW + qx * 8) = o;
}

// ---------------- pass 2: LDS-tiled warp + loss, partials out ----------------
__global__ __launch_bounds__(256) void loss_kernel(
    const float* __restrict__ prev, const _Float16* __restrict__ gpad,
    const float* __restrict__ flow, double* __restrict__ psum,
    unsigned int* __restrict__ pcnt)
{
    __shared__ __align__(16) _Float16 smh[TW * TH];   // 19.2 KB
    __shared__ __align__(16) float    smf[FLOW_F];    // 10 KB

    // XCD-chunked: 8 XCDs x 256 contiguous blocks (= 2 images each).
    const int bid = ((blockIdx.x & 7) << 8) | (blockIdx.x >> 3);
    const int b   = bid >> 7;              // 128 tiles per image
    const int t   = bid & 127;
    const int tx  = t & 7;                 // 8 x-tiles (64 wide)
    const int ty  = t >> 3;                // 16 y-tiles (32 tall)
    const int x0t = tx * TX;
    const int y0t = ty * TY;

    const float fr = (float)(127.0 / 511.0);
    const int fy_lo = (int)((float)y0t * fr);

    const _Float16* __restrict__ gb = gpad + (long)b * PIMG;

    // ---- stage gray tile: y in [y0t-24, y0t+56), x in [x0t-24, x0t+96)
    {
        const _Float16* __restrict__ src = gb + (y0t + 8) * PW + (x0t + 8);
        for (int it = threadIdx.x; it < TH * (TW / 8); it += 256) {
            const int r = it / (TW / 8), c = it - r * (TW / 8);
            *(uint4*)(smh + r * TW + c * 8) = *(const uint4*)(src + r * PW + c * 8);
        }
        const float* __restrict__ fsrc = flow + (long)b * 2 * FHW;
        for (int it = threadIdx.x; it < 2 * FROWS * (FW / 4); it += 256) {
            const int c    = it / (FROWS * (FW / 4));
            const int rr   = (it - c * (FROWS * (FW / 4))) >> 5;
            const int c4   = it & 31;
            const int frow = min(fy_lo + rr, FH - 1);
            const float4 v = *(const float4*)(fsrc + c * FHW + frow * FW + c4 * 4);
            *(float4*)(smf + c * (FROWS * FW) + rr * FW + c4 * 4) = v;
        }
    }

    // ---- prev grayscale: thread = 4 consecutive x in rows yl and yl+16
    const int xq = threadIdx.x & 15;
    const int yl = threadIdx.x >> 4;
    const int xb = x0t + xq * 4;

    float pg[2][4];
    #pragma unroll
    for (int k = 0; k < 2; ++k) {
        const int y = y0t + yl + k * 16;
        const float* __restrict__ pb = prev + (long)b * IMG + y * W + xb;
        const float4 pr  = *(const float4*)(pb);
        const float4 pgc = *(const float4*)(pb + HW);
        const float4 plc = *(const float4*)(pb + 2 * HW);
        pg[k][0] = 0.299f * pr.x + 0.587f * pgc.x + 0.114f * plc.x;
        pg[k][1] = 0.299f * pr.y + 0.587f * pgc.y + 0.114f * plc.y;
        pg[k][2] = 0.299f * pr.z + 0.587f * pgc.z + 0.114f * plc.z;
        pg[k][3] = 0.299f * pr.w + 0.587f * pgc.w + 0.114f * plc.w;
    }

    __syncthreads();

    const float sxfb = (float)xb * fr;
    const int F  = (int)sxfb;
    const int F2 = min(F + 2, FW - 1);

    double lsum = 0.0;
    unsigned int lcnt = 0;

    #pragma unroll
    for (int k = 0; k < 2; ++k) {
        const int y = y0t + yl + k * 16;

        // flow values (row-shared fy; 3 columns cover the 4 pixels)
        const float syf = (float)y * fr;
        const int   fy0 = (int)syf;
        const float wy  = syf - (float)fy0;
        const int r0 = fy0 - fy_lo;
        const int r1 = min(fy0 + 1, FH - 1) - fy_lo;

        const float* __restrict__ su = smf;
        const float* __restrict__ sv = smf + FROWS * FW;
        const float u0a = su[r0 * FW + F], u0b = su[r0 * FW + F + 1], u0c = su[r0 * FW + F2];
        const float u1a = su[r1 * FW + F], u1b = su[r1 * FW + F + 1], u1c = su[r1 * FW + F2];
        const float v0a = sv[r0 * FW + F], v0b = sv[r0 * FW + F + 1], v0c = sv[r0 * FW + F2];
        const float v1a = sv[r1 * FW + F], v1b = sv[r1 * FW + F + 1], v1c = sv[r1 * FW + F2];

        #pragma unroll
        for (int i = 0; i < 4; ++i) {
            const int x = xb + i;
            const float sxf = (float)x * fr;
            const int   fx0 = (int)sxf;
            const float wx  = sxf - (float)fx0;
            const int   d   = fx0 - F;   // 0 or 1

            const float u00 = d ? u0b : u0a, u01 = d ? u0c : u0b;
            const float u10 = d ? u1b : u1a, u11 = d ? u1c : u1b;
            const float v00 = d ? v0b : v0a, v01 = d ? v0c : v0b;
            const float v10 = d ? v1b : v1a, v11 = d ? v1c : v1b;

            // row-lerp then col-lerp (reference op order), then *4 scale
            const float uc0 = u00 * (1.0f - wy) + u10 * wy;
            const float uc1 = u01 * (1.0f - wy) + u11 * wy;
            const float vc0 = v00 * (1.0f - wy) + v10 * wy;
            const float vc1 = v01 * (1.0f - wy) + v11 * wy;
            const float u = (uc0 * (1.0f - wx) + uc1 * wx) * 4.0f;
            const float v = (vc0 * (1.0f - wx) + vc1 * wx) * 4.0f;

            const float gx = (float)x + u;
            const float gy = (float)y + v;
            const float vm = ((gx >= 0.0f) & (gx <= (float)(W - 1)) &
                              (gy >= 0.0f) & (gy <= (float)(H - 1))) ? 1.0f : 0.0f;

            const float gxf = floorf(gx), gyf = floorf(gy);
            const float wwx = gx - gxf,  wwy = gy - gyf;
            const int ix0 = (int)gxf, iy0 = (int)gyf;

            const int cx = ix0 - (x0t - 24);
            const int ry = iy0 - (y0t - 24);
            float c00, c01, c10, c11;
            if ((unsigned)cx <= (unsigned)(TW - 2) && (unsigned)ry <= (unsigned)(TH - 2)) {
                const int la = ry * TW + cx;
                c00 = (float)smh[la];      c01 = (float)smh[la + 1];
                c10 = (float)smh[la + TW]; c11 = (float)smh[la + TW + 1];
            } else {
                // rare: clamp into padded region (zeros outside image keep
                // per-corner semantics exact for any valid pixel)
                const int iyc = min(max(iy0, -P), PH - P - 2);
                const int ixc = min(max(ix0, -P), PW - P - 2);
                const _Float16* __restrict__ gp = gb + (iyc + P) * PW + (ixc + P);
                c00 = (float)gp[0];  c01 = (float)gp[1];
                c10 = (float)gp[PW]; c11 = (float)gp[PW + 1];
            }

            const float warped = c00 * (1.0f - wwx) * (1.0f - wwy)
                               + c01 * wwx * (1.0f - wwy)
                               + c10 * (1.0f - wwx) * wwy
                               + c11 * wwx * wwy;
            const float diff = pg[k][i] - warped;
            const float l = sqrtf(diff * diff + EPS * EPS);
            lsum += (double)(l * vm);
            lcnt += (unsigned int)vm;
        }
    }

    // ---- wave64 + block reduce; ONE partial store per block (no atomics) ----
    #pragma unroll
    for (int off = 32; off > 0; off >>= 1) {
        lsum += __shfl_down(lsum, off);
        lcnt += __shfl_down(lcnt, off);
    }
    __shared__ double s_sum[4];
    __shared__ unsigned int s_cnt[4];
    const int wid = threadIdx.x >> 6, lane = threadIdx.x & 63;
    if (lane == 0) { s_sum[wid] = lsum; s_cnt[wid] = lcnt; }
    __syncthreads();
    if (threadIdx.x == 0) {
        psum[blockIdx.x] = s_sum[0] + s_sum[1] + s_sum[2] + s_sum[3];
        pcnt[blockIdx.x] = s_cnt[0] + s_cnt[1] + s_cnt[2] + s_cnt[3];
    }
}

// ---------------- pass 3: reduce partials ----------------
__global__ __launch_bounds__(256) void reduce_kernel(
    const double* __restrict__ psum, const unsigned int* __restrict__ pcnt,
    int nb, float* __restrict__ out)
{
    double s = 0.0;
    unsigned long long c = 0;
    for (int i = threadIdx.x; i < nb; i += 256) {
        s += psum[i];
        c += (unsigned long long)pcnt[i];
    }
    #pragma unroll
    for (int off = 32; off > 0; off >>= 1) {
        s += __shfl_down(s, off);
        c += __shfl_down(c, off);
    }
    __shared__ double ss[4];
    __shared__ unsigned long long sc[4];
    const int wid = threadIdx.x >> 6, lane = threadIdx.x & 63;
    if (lane == 0) { ss[wid] = s; sc[wid] = c; }
    __syncthreads();
    if (threadIdx.x == 0) {
        double ts = ss[0] + ss[1] + ss[2] + ss[3];
        double tc = (double)(sc[0] + sc[1] + sc[2] + sc[3]);
        if (tc < 1.0) tc = 1.0;
        const float loss = (float)(ts / tc);
        out[0] = loss;
        out[1] = loss;
    }
}

// ---------------- fallback single-pass (if ws too small) ----------------
__device__ __forceinline__ float gray3(const float* __restrict__ img, int off) {
    return 0.299f * img[off] + 0.587f * img[HW + off] + 0.114f * img[2 * HW + off];
}

__global__ __launch_bounds__(256) void flow_loss_mono_kernel(
    const float* __restrict__ prev, const float* __restrict__ nxt,
    const float* __restrict__ flow, double* __restrict__ psum,
    unsigned int* __restrict__ pcnt)
{
    const int nquad = B * HW / 4;
    const float fr = (float)(127.0 / 511.0);
    double lsum = 0.0;
    unsigned int lcnt = 0;
    for (int q = blockIdx.x * blockDim.x + threadIdx.x; q < nquad;
         q += gridDim.x * blockDim.x) {
        const int pix = q * 4;
        const int b   = pix >> 18;
        const int rem = pix & (HW - 1);
        const int y   = rem >> 9;
        const int x0  = rem & 511;
        const float* __restrict__ pb = prev + (long)b * IMG;
        const float* __restrict__ nb = nxt  + (long)b * IMG;
        const float* __restrict__ fu = flow + (long)b * 2 * FHW;
        const float* __restrict__ fv = fu + FHW;
        const float syf = (float)y * fr;
        const int   fy0 = (int)syf;
        const int   fy1 = min(fy0 + 1, FH - 1);
        const float wy  = syf - (float)fy0;
        #pragma unroll
        for (int i = 0; i < 4; ++i) {
            const int x = x0 + i;
            const float sxf = (float)x * fr;
            const int   fx0 = (int)sxf;
            const int   fx1 = min(fx0 + 1, FW - 1);
            const float wx  = sxf - (float)fx0;
            const float uc0 = fu[fy0 * FW + fx0] * (1.0f - wy) + fu[fy1 * FW + fx0] * wy;
            const float uc1 = fu[fy0 * FW + fx1] * (1.0f - wy) + fu[fy1 * FW + fx1] * wy;
            const float vc0 = fv[fy0 * FW + fx0] * (1.0f - wy) + fv[fy1 * FW + fx0] * wy;
            const float vc1 = fv[fy0 * FW + fx1] * (1.0f - wy) + fv[fy1 * FW + fx1] * wy;
            const float u = (uc0 * (1.0f - wx) + uc1 * wx) * 4.0f;
            const float v = (vc0 * (1.0f - wx) + vc1 * wx) * 4.0f;
            const float gx = (float)x + u;
            const float gy = (float)y + v;
            const float vm = ((gx >= 0.0f) & (gx <= (float)(W - 1)) &
                              (gy >= 0.0f) & (gy <= (float)(H - 1))) ? 1.0f : 0.0f;
            const float gxf = floorf(gx), gyf = floorf(gy);
            const float wwx = gx - gxf, wwy = gy - gyf;
            const int ix0 = (int)gxf, iy0 = (int)gyf;
            const int xc0 = min(max(ix0, 0), W - 1), xc1 = min(max(ix0 + 1, 0), W - 1);
            const int yc0 = min(max(iy0, 0), H - 1), yc1 = min(max(iy0 + 1, 0), H - 1);
            const float okx0 = (ix0 >= 0 && ix0 < W) ? 1.f : 0.f;
            const float okx1 = (ix0 + 1 >= 0 && ix0 + 1 < W) ? 1.f : 0.f;
            const float oky0 = (iy0 >= 0 && iy0 < H) ? 1.f : 0.f;
            const float oky1 = (iy0 + 1 >= 0 && iy0 + 1 < H) ? 1.f : 0.f;
            const float c00 = gray3(nb, yc0 * W + xc0) * oky0 * okx0;
            const float c01 = gray3(nb, yc0 * W + xc1) * oky0 * okx1;
            const float c10 = gray3(nb, yc1 * W + xc0) * oky1 * okx0;
            const float c11 = gray3(nb, yc1 * W + xc1) * oky1 * okx1;
            const float warped = c00 * (1.0f - wwx) * (1.0f - wwy)
                               + c01 * wwx * (1.0f - wwy)
                               + c10 * (1.0f - wwx) * wwy
                               + c11 * wwx * wwy;
            const float pgv = gray3(pb, y * W + x);
            const float diff = pgv - warped;
            const float l = sqrtf(diff * diff + EPS * EPS);
            lsum += (double)(l * vm);
            lcnt += (unsigned int)vm;
        }
    }
    #pragma unroll
    for (int off = 32; off > 0; off >>= 1) {
        lsum += __shfl_down(lsum, off);
        lcnt += __shfl_down(lcnt, off);
    }
    __shared__ double s_sum[4];
    __shared__ unsigned int s_cnt[4];
    const int wid = threadIdx.x >> 6, lane = threadIdx.x & 63;
    if (lane == 0) { s_sum[wid] = lsum; s_cnt[wid] = lcnt; }
    __syncthreads();
    if (threadIdx.x == 0) {
        psum[blockIdx.x] = s_sum[0] + s_sum[1] + s_sum[2] + s_sum[3];
        pcnt[blockIdx.x] = s_cnt[0] + s_cnt[1] + s_cnt[2] + s_cnt[3];
    }
}

extern "C" void kernel_launch(void* const* d_in, const int* in_sizes, int n_in,
                              void* d_out, int out_size, void* d_ws, size_t ws_size,
                              hipStream_t stream) {
    const float* prev = (const float*)d_in[0];
    const float* nxt  = (const float*)d_in[1];
    const float* flow = (const float*)d_in[2];
    float* out = (float*)d_out;

    // ws layout: [0, NB*8) double partial sums; [NB*8, NB*12) uint counts;
    //            [4096-aligned] padded fp16 gray buffer (10.6 MB)
    double* psum = (double*)d_ws;
    unsigned int* pcnt = (unsigned int*)((char*)d_ws + NB * 8);
    const size_t gbuf_off = ((size_t)NB * 12 + 4095) & ~(size_t)4095;
    const size_t pad_bytes = (size_t)B * PIMG * sizeof(_Float16);

    if (ws_size >= gbuf_off + pad_bytes) {
        _Float16* gbuf = (_Float16*)((char*)d_ws + gbuf_off);
        pad_gray_kernel<<<dim3(B * PQ8 / 256), dim3(256), 0, stream>>>(nxt, gbuf);
        loss_kernel<<<dim3(NB), dim3(256), 0, stream>>>(
            prev, gbuf, flow, psum, pcnt);
        reduce_kernel<<<dim3(1), dim3(256), 0, stream>>>(psum, pcnt, NB, out);
    } else {
        flow_loss_mono_kernel<<<dim3(2048), dim3(256), 0, stream>>>(
            prev, nxt, flow, psum, pcnt);
        reduce_kernel<<<dim3(1), dim3(256), 0, stream>>>(psum, pcnt, 2048, out);
    }
}